// Round 1
// baseline (189.930 us; speedup 1.0000x reference)
//
#include <hip/hip_runtime.h>
#include <stdint.h>

// ---------- types ----------
typedef __attribute__((ext_vector_type(8))) short s8v;   // 8 bf16 (4 VGPRs)
typedef __attribute__((ext_vector_type(4))) float f4v;   // MFMA accumulator

// ---------- helpers ----------
__device__ __forceinline__ unsigned short f2bf(float f) {
  unsigned u = __float_as_uint(f);
  u = u + 0x7FFFu + ((u >> 16) & 1u);   // RNE
  return (unsigned short)(u >> 16);
}
// monotone float->uint map: order(enc(a)) == order(a). enc range min (0) < enc(-inf).
__device__ __forceinline__ unsigned encf(float f) {
  unsigned i = __float_as_uint(f);
  return (i & 0x80000000u) ? ~i : (i | 0x80000000u);
}
__device__ __forceinline__ float decf(unsigned u) {
  unsigned i = (u & 0x80000000u) ? (u & 0x7FFFFFFFu) : ~u;
  return __uint_as_float(i);
}
__device__ __forceinline__ void gload_lds16(const unsigned short* g, unsigned short* l) {
  // wave-uniform LDS base + lane*16 semantics; our layout is linear in tid so it matches.
  __builtin_amdgcn_global_load_lds((const __attribute__((address_space(1))) void*)g,
                                   (__attribute__((address_space(3))) void*)l, 16, 0, 0);
}

// ---------- fp32 -> bf16 conversion for q and a ----------
__global__ void convert_qa_kernel(const float4* __restrict__ q, const float4* __restrict__ a,
                                  ushort4* __restrict__ qb, ushort4* __restrict__ ab) {
  const int i = blockIdx.x * 256 + threadIdx.x;
  float4 v = q[i];
  qb[i] = make_ushort4(f2bf(v.x), f2bf(v.y), f2bf(v.z), f2bf(v.w));
  float4 w = a[i];
  ab[i] = make_ushort4(f2bf(w.x), f2bf(w.y), f2bf(w.z), f2bf(w.w));
}

// ---------- U (DxD fp32) -> Ut (bf16, transposed: Ut[n][k] = U[k][n]) ----------
__global__ void convert_u_kernel(const float* __restrict__ U, unsigned short* __restrict__ Ut) {
  const int k = blockIdx.x;
  const int n = threadIdx.x;
  Ut[n * 256 + k] = f2bf(U[k * 256 + n]);
}

// ---------- GEMM C[m,n] = sum_k A[m,k]*B[n,k]  (both row-major, K=256, ld=256) ----------
// MODE 0: store C as bf16 (used for qU = q @ U via Ut)
// MODE 1: reduce row/col maxes of C into encoded-uint global arrays (used for S = qU @ a^T)
template<int MODE>
__global__ void gemm_bt(const unsigned short* __restrict__ A,
                        const unsigned short* __restrict__ Bm,
                        long strideA, long strideB,
                        unsigned short* __restrict__ C,
                        unsigned* __restrict__ rowmax,
                        unsigned* __restrict__ colmax) {
  __shared__ unsigned short As[128 * 64];   // 16 KB
  __shared__ unsigned short Bs[128 * 64];   // 16 KB
  __shared__ unsigned rowLds[128];
  __shared__ unsigned colLds[128];

  const int tid  = threadIdx.x;
  const int tm   = blockIdx.x, tn = blockIdx.y, b = blockIdx.z;
  const unsigned short* Ab = A + (long)b * strideA + (long)tm * 128 * 256;
  const unsigned short* Bb = Bm + (long)b * strideB + (long)tn * 128 * 256;

  const int lane = tid & 63;
  const int m16  = lane & 15;
  const int quad = lane >> 4;
  const int wave = tid >> 6;
  const int wm   = wave >> 1, wn = wave & 1;
  const int srow = tid >> 3;          // staging row 0..31 (per 32-row issue)
  const int scol = (tid & 7) * 8;     // staging col 0,8,...,56

  if (MODE == 1 && tid < 128) { rowLds[tid] = 0u; colLds[tid] = 0u; }

  f4v acc[4][4] = {};

  for (int kt = 0; kt < 4; ++kt) {
    const int k0 = kt * 64;
    __syncthreads();                  // LDS free from previous iter
    #pragma unroll
    for (int i = 0; i < 4; ++i) {
      const int r = i * 32 + srow;
      gload_lds16(Ab + (long)r * 256 + k0 + scol, &As[i * 2048 + tid * 8]);
    }
    #pragma unroll
    for (int i = 0; i < 4; ++i) {
      const int r = i * 32 + srow;
      gload_lds16(Bb + (long)r * 256 + k0 + scol, &Bs[i * 2048 + tid * 8]);
    }
    __syncthreads();                  // staging complete (compiler waits vmcnt)
    #pragma unroll
    for (int kk = 0; kk < 2; ++kk) {
      const int ko = kk * 32 + quad * 8;
      s8v af[4], bfv[4];
      #pragma unroll
      for (int i = 0; i < 4; ++i) af[i] = *(const s8v*)&As[(wm * 64 + i * 16 + m16) * 64 + ko];
      #pragma unroll
      for (int j = 0; j < 4; ++j) bfv[j] = *(const s8v*)&Bs[(wn * 64 + j * 16 + m16) * 64 + ko];
      #pragma unroll
      for (int i = 0; i < 4; ++i)
        #pragma unroll
        for (int j = 0; j < 4; ++j)
          acc[i][j] = __builtin_amdgcn_mfma_f32_16x16x32_bf16(af[i], bfv[j], acc[i][j], 0, 0, 0);
    }
  }

  if (MODE == 0) {
    // C/D layout: col = lane&15, row = quad*4 + reg  (verified mapping)
    #pragma unroll
    for (int i = 0; i < 4; ++i)
      #pragma unroll
      for (int r = 0; r < 4; ++r) {
        const long row = (long)tm * 128 + wm * 64 + i * 16 + quad * 4 + r;
        #pragma unroll
        for (int j = 0; j < 4; ++j) {
          const int col = tn * 128 + wn * 64 + j * 16 + m16;
          C[row * 256 + col] = f2bf(acc[i][j][r]);
        }
      }
  } else {
    // ---- row maxes: lane covers rows (i*16 + quad*4 + r), cols (j*16 + m16) ----
    #pragma unroll
    for (int i = 0; i < 4; ++i)
      #pragma unroll
      for (int r = 0; r < 4; ++r) {
        float v = fmaxf(fmaxf(acc[i][0][r], acc[i][1][r]), fmaxf(acc[i][2][r], acc[i][3][r]));
        #pragma unroll
        for (int d2 = 1; d2 < 16; d2 <<= 1) v = fmaxf(v, __shfl_xor(v, d2));  // over m16
        if (m16 == 0) atomicMax(&rowLds[wm * 64 + i * 16 + quad * 4 + r], encf(v));
      }
    // ---- col maxes ----
    #pragma unroll
    for (int j = 0; j < 4; ++j) {
      float v = -3.4e38f;
      #pragma unroll
      for (int i = 0; i < 4; ++i)
        #pragma unroll
        for (int r = 0; r < 4; ++r) v = fmaxf(v, acc[i][j][r]);
      v = fmaxf(v, __shfl_xor(v, 16));   // over quads
      v = fmaxf(v, __shfl_xor(v, 32));
      if (quad == 0) atomicMax(&colLds[wn * 64 + j * 16 + m16], encf(v));
    }
    __syncthreads();
    if (tid < 128) {
      atomicMax(&rowmax[(long)b * 2048 + tm * 128 + tid], rowLds[tid]);
    } else {
      atomicMax(&colmax[(long)b * 2048 + tn * 128 + (tid - 128)], colLds[tid - 128]);
    }
  }
}

// ---------- softmax over T of tanh(max): g = softmax(tanh(decoded maxes)) ----------
__global__ void softmax_kernel(const unsigned* __restrict__ rowmax, const unsigned* __restrict__ colmax,
                               float* __restrict__ gq, float* __restrict__ ga) {
  const int b = blockIdx.x;
  const unsigned* e = blockIdx.y ? colmax : rowmax;
  float* g = blockIdx.y ? ga : gq;
  const int tid = threadIdx.x;
  float x[8];
  float m = -3.4e38f;
  #pragma unroll
  for (int j = 0; j < 8; ++j) {
    x[j] = tanhf(decf(e[b * 2048 + j * 256 + tid]));
    m = fmaxf(m, x[j]);
  }
  #pragma unroll
  for (int d2 = 1; d2 < 64; d2 <<= 1) m = fmaxf(m, __shfl_xor(m, d2));
  __shared__ float sred[4];
  __shared__ float sred2[4];
  if ((tid & 63) == 0) sred[tid >> 6] = m;
  __syncthreads();
  m = fmaxf(fmaxf(sred[0], sred[1]), fmaxf(sred[2], sred[3]));
  float s = 0.f;
  #pragma unroll
  for (int j = 0; j < 8; ++j) { x[j] = expf(x[j] - m); s += x[j]; }
  #pragma unroll
  for (int d2 = 1; d2 < 64; d2 <<= 1) s += __shfl_xor(s, d2);
  if ((tid & 63) == 0) sred2[tid >> 6] = s;
  __syncthreads();
  s = sred2[0] + sred2[1] + sred2[2] + sred2[3];
  const float inv = 1.f / s;
  #pragma unroll
  for (int j = 0; j < 8; ++j) g[b * 2048 + j * 256 + tid] = x[j] * inv;
}

// ---------- weighted sum: out[b,d] = sum_t src[b,t,d] * g[b,t]  (fp32 inputs) ----------
__global__ void wsum_kernel(const float* __restrict__ q, const float* __restrict__ a,
                            const float* __restrict__ gq, const float* __restrict__ ga,
                            float* __restrict__ out) {
  const int d = threadIdx.x;
  const int chunk = blockIdx.x;   // 16 chunks of 128 rows
  const int b = blockIdx.y;
  const int z = blockIdx.z;       // 0: q_out, 1: a_out
  const float* src = z ? a : q;
  const float* g = z ? ga : gq;
  float acc = 0.f;
  const int t0 = chunk * 128;
  const float* srow = src + ((long)b * 2048 + t0) * 256 + d;
  const float* grow = g + b * 2048 + t0;
  #pragma unroll 8
  for (int t = 0; t < 128; ++t) acc += srow[(long)t * 256] * grow[t];
  atomicAdd(&out[z * 4096 + b * 256 + d], acc);
}

// ---------- launch ----------
extern "C" void kernel_launch(void* const* d_in, const int* in_sizes, int n_in,
                              void* d_out, int out_size, void* d_ws, size_t ws_size,
                              hipStream_t stream) {
  const float* q = (const float*)d_in[0];
  const float* a = (const float*)d_in[1];
  const float* U = (const float*)d_in[2];
  float* out = (float*)d_out;

  // workspace layout (bytes):
  //   [0,16M)    q_bf16      [16M,32M) a_bf16     [32M,48M) qU_bf16
  //   [48M, +128K) Ut_bf16   then rmax(128K), cmax(128K), gq(128K), ga(128K)
  char* w = (char*)d_ws;
  unsigned short* qb = (unsigned short*)w;
  unsigned short* ab = (unsigned short*)(w + (16ull << 20));
  unsigned short* qU = (unsigned short*)(w + (32ull << 20));
  unsigned short* Ut = (unsigned short*)(w + (48ull << 20));
  unsigned* rmax = (unsigned*)(w + (48ull << 20) + (128ull << 10));
  unsigned* cmax = rmax + 32768;
  float* gq = (float*)(cmax + 32768);
  float* ga = gq + 32768;

  // encoded-max init: 0 is the minimum of the encoding; out zeroed for atomicAdd
  hipMemsetAsync(rmax, 0, 2 * 32768 * sizeof(unsigned), stream);
  hipMemsetAsync(out, 0, 8192 * sizeof(float), stream);

  convert_qa_kernel<<<8192, 256, 0, stream>>>((const float4*)q, (const float4*)a,
                                              (ushort4*)qb, (ushort4*)ab);
  convert_u_kernel<<<256, 256, 0, stream>>>(U, Ut);

  // qU[m,n] = sum_k q[m,k] * Ut[n,k]; M = B*T = 32768, N = 256
  gemm_bt<0><<<dim3(256, 2, 1), 256, 0, stream>>>(qb, Ut, 0, 0, qU, nullptr, nullptr);

  // S[b] row/col maxes: per-batch 2048x2048, tiles 128x128
  gemm_bt<1><<<dim3(16, 16, 16), 256, 0, stream>>>(qU, ab, 2048 * 256, 2048 * 256,
                                                   nullptr, rmax, cmax);

  softmax_kernel<<<dim3(16, 2), 256, 0, stream>>>(rmax, cmax, gq, ga);
  wsum_kernel<<<dim3(16, 16, 2), 256, 0, stream>>>(q, a, gq, ga, out);
}

// Round 4
// 183.742 us; speedup vs baseline: 1.0337x; 1.0337x over previous
//
#include <hip/hip_runtime.h>
#include <stdint.h>

// ---------- types ----------
typedef __attribute__((ext_vector_type(8))) short s8v;   // 8 bf16 (4 VGPRs)
typedef __attribute__((ext_vector_type(4))) float f4v;   // MFMA accumulator

// ---------- helpers ----------
__device__ __forceinline__ unsigned short f2bf(float f) {
  unsigned u = __float_as_uint(f);
  u = u + 0x7FFFu + ((u >> 16) & 1u);   // RNE
  return (unsigned short)(u >> 16);
}
__device__ __forceinline__ float bf2f(unsigned short h) {
  return __uint_as_float((unsigned)h << 16);
}
// monotone float->uint map: order(enc(a)) == order(a); 0 is below enc of any real float.
__device__ __forceinline__ unsigned encf(float f) {
  unsigned i = __float_as_uint(f);
  return (i & 0x80000000u) ? ~i : (i | 0x80000000u);
}
__device__ __forceinline__ float decf(unsigned u) {
  unsigned i = (u & 0x80000000u) ? (u & 0x7FFFFFFFu) : ~u;
  return __uint_as_float(i);
}
__device__ __forceinline__ void gload_lds16(const unsigned short* g, unsigned short* l) {
  __builtin_amdgcn_global_load_lds((const __attribute__((address_space(1))) void*)g,
                                   (__attribute__((address_space(3))) void*)l, 16, 0, 0);
}

// ---------- fp32 -> bf16 conversion for q and a ----------
__global__ void convert_qa_kernel(const float4* __restrict__ q, const float4* __restrict__ a,
                                  ushort4* __restrict__ qb, ushort4* __restrict__ ab) {
  const int i = blockIdx.x * 256 + threadIdx.x;
  float4 v = q[i];
  qb[i] = make_ushort4(f2bf(v.x), f2bf(v.y), f2bf(v.z), f2bf(v.w));
  float4 w = a[i];
  ab[i] = make_ushort4(f2bf(w.x), f2bf(w.y), f2bf(w.z), f2bf(w.w));
}

// ---------- U (DxD fp32) -> Ut (bf16, transposed: Ut[n][k] = U[k][n]) ----------
__global__ void convert_u_kernel(const float* __restrict__ U, unsigned short* __restrict__ Ut) {
  const int k = blockIdx.x;
  const int n = threadIdx.x;
  Ut[n * 256 + k] = f2bf(U[k * 256 + n]);
}

// ---------- GEMM C[m,n] = sum_k A[m,k]*B[n,k]  (row-major, K=256, ld=256) ----------
// LDS layout XOR-swizzled: element (row, 16B-chunk c) lives at chunk c ^ (row&7).
// global_load_lds forces lane-linear LDS dests, so staging permutes the GLOBAL
// source chunk instead (exact inverse: staging base rows are multiples of 8).
// Kills the 16-way ds_read bank conflict of the unswizzled stride-128B layout.
// MODE 0: store C bf16 (qU = q @ U). MODE 1: row/col maxes -> encoded-uint atomics.
template<int WM, int WN, int MODE>
__global__ void gemm_bt(const unsigned short* __restrict__ A,
                        const unsigned short* __restrict__ Bm,
                        long strideA, long strideB,
                        unsigned short* __restrict__ C,
                        unsigned* __restrict__ rowmax,
                        unsigned* __restrict__ colmax) {
  constexpr int T = WM * WN * 64;        // threads
  constexpr int AROWS = WM * 64;
  constexpr int BROWS = WN * 64;
  constexpr int RPI = T / 8;             // rows staged per issue

  __shared__ unsigned short As[AROWS * 64];
  __shared__ unsigned short Bs[BROWS * 64];
  __shared__ unsigned rowLds[AROWS];
  __shared__ unsigned colLds[BROWS];

  const int tid  = threadIdx.x;
  const int tm   = blockIdx.x, tn = blockIdx.y, b = blockIdx.z;
  const unsigned short* Ab = A + (long)b * strideA + (long)tm * AROWS * 256;
  const unsigned short* Bb = Bm + (long)b * strideB + (long)tn * BROWS * 256;

  const int lane = tid & 63;
  const int m16  = lane & 15;
  const int quad = lane >> 4;
  const int wave = tid >> 6;
  const int wm   = wave / WN, wn = wave % WN;
  const int srow = tid >> 3;                                // staging row within issue
  const int scol = (((tid & 7) ^ (srow & 7))) * 8;          // swizzled global source chunk

  if (MODE == 1) {
    if (tid < AROWS) rowLds[tid] = 0u;
    if (tid < BROWS) colLds[tid] = 0u;
  }

  f4v acc[4][4] = {};

  for (int kt = 0; kt < 4; ++kt) {
    const int k0 = kt * 64;
    __syncthreads();                  // LDS free from previous iter
    #pragma unroll
    for (int i = 0; i < AROWS / RPI; ++i) {
      const int r = i * RPI + srow;
      gload_lds16(Ab + (long)r * 256 + k0 + scol, &As[i * RPI * 64 + tid * 8]);
    }
    #pragma unroll
    for (int i = 0; i < BROWS / RPI; ++i) {
      const int r = i * RPI + srow;
      gload_lds16(Bb + (long)r * 256 + k0 + scol, &Bs[i * RPI * 64 + tid * 8]);
    }
    __syncthreads();                  // staging complete
    #pragma unroll
    for (int kk = 0; kk < 2; ++kk) {
      const int cs = ((kk * 4 + quad) ^ (m16 & 7)) * 8;   // read-side swizzle (row&7 == m16&7)
      s8v af[4], bfv[4];
      #pragma unroll
      for (int i = 0; i < 4; ++i)
        af[i] = *(const s8v*)&As[(wm * 64 + i * 16 + m16) * 64 + cs];
      #pragma unroll
      for (int j = 0; j < 4; ++j)
        bfv[j] = *(const s8v*)&Bs[(wn * 64 + j * 16 + m16) * 64 + cs];
      #pragma unroll
      for (int i = 0; i < 4; ++i)
        #pragma unroll
        for (int j = 0; j < 4; ++j)
          acc[i][j] = __builtin_amdgcn_mfma_f32_16x16x32_bf16(af[i], bfv[j], acc[i][j], 0, 0, 0);
    }
  }

  if (MODE == 0) {
    // C/D layout: col = lane&15, row = quad*4 + reg  (verified mapping)
    #pragma unroll
    for (int i = 0; i < 4; ++i)
      #pragma unroll
      for (int r = 0; r < 4; ++r) {
        const long row = (long)tm * AROWS + wm * 64 + i * 16 + quad * 4 + r;
        #pragma unroll
        for (int j = 0; j < 4; ++j) {
          const int col = tn * BROWS + wn * 64 + j * 16 + m16;
          C[row * 256 + col] = f2bf(acc[i][j][r]);
        }
      }
  } else {
    // ---- row maxes ----
    #pragma unroll
    for (int i = 0; i < 4; ++i)
      #pragma unroll
      for (int r = 0; r < 4; ++r) {
        float v = fmaxf(fmaxf(acc[i][0][r], acc[i][1][r]), fmaxf(acc[i][2][r], acc[i][3][r]));
        #pragma unroll
        for (int d2 = 1; d2 < 16; d2 <<= 1) v = fmaxf(v, __shfl_xor(v, d2));
        if (m16 == 0) atomicMax(&rowLds[wm * 64 + i * 16 + quad * 4 + r], encf(v));
      }
    // ---- col maxes ----
    #pragma unroll
    for (int j = 0; j < 4; ++j) {
      float v = -3.4e38f;
      #pragma unroll
      for (int i = 0; i < 4; ++i)
        #pragma unroll
        for (int r = 0; r < 4; ++r) v = fmaxf(v, acc[i][j][r]);
      v = fmaxf(v, __shfl_xor(v, 16));
      v = fmaxf(v, __shfl_xor(v, 32));
      if (quad == 0) atomicMax(&colLds[wn * 64 + j * 16 + m16], encf(v));
    }
    __syncthreads();
    if (tid < AROWS) {
      atomicMax(&rowmax[(long)b * 2048 + tm * AROWS + tid], rowLds[tid]);
    } else if (tid < AROWS + BROWS) {
      atomicMax(&colmax[(long)b * 2048 + tn * BROWS + (tid - AROWS)], colLds[tid - AROWS]);
    }
  }
}

// ---------- fused softmax + weighted sum (bf16 inputs, fp32 accumulate) ----------
// block (chunk 0..15, b 0..15, z 0..1); each block re-derives the softmax stats
// (cheap: 2048 loads) then does 128 rows of the weighted sum.
__global__ void wsum_kernel(const ushort4* __restrict__ qb, const ushort4* __restrict__ ab,
                            const unsigned* __restrict__ rowmax, const unsigned* __restrict__ colmax,
                            float* __restrict__ out) {
  const int tid = threadIdx.x;
  const int chunk = blockIdx.x;
  const int b = blockIdx.y;
  const int z = blockIdx.z;
  const unsigned* e = z ? colmax : rowmax;
  const ushort4* src = z ? ab : qb;

  __shared__ float sm[4];
  __shared__ float ss[4];
  __shared__ float wLds[128];
  __shared__ float red[256 * 4];

  // softmax stats over all 2048 positions of batch b
  float x[8];
  float m = -3.4e38f;
  #pragma unroll
  for (int j = 0; j < 8; ++j) {
    x[j] = tanhf(decf(e[b * 2048 + j * 256 + tid]));
    m = fmaxf(m, x[j]);
  }
  #pragma unroll
  for (int d2 = 1; d2 < 64; d2 <<= 1) m = fmaxf(m, __shfl_xor(m, d2));
  if ((tid & 63) == 0) sm[tid >> 6] = m;
  __syncthreads();
  m = fmaxf(fmaxf(sm[0], sm[1]), fmaxf(sm[2], sm[3]));
  float s = 0.f;
  #pragma unroll
  for (int j = 0; j < 8; ++j) s += expf(x[j] - m);
  #pragma unroll
  for (int d2 = 1; d2 < 64; d2 <<= 1) s += __shfl_xor(s, d2);
  if ((tid & 63) == 0) ss[tid >> 6] = s;
  __syncthreads();
  const float inv = 1.f / (ss[0] + ss[1] + ss[2] + ss[3]);

  // weights for this chunk's 128 rows
  if (tid < 128) {
    float xv = tanhf(decf(e[b * 2048 + chunk * 128 + tid]));
    wLds[tid] = expf(xv - m) * inv;
  }
  __syncthreads();

  // weighted sum: thread handles d-group (tid&63)*4, row-group tid>>6 (stride 4)
  const int dg = tid & 63;     // ushort4 index: d = dg*4..dg*4+3
  const int rg = tid >> 6;
  float a0 = 0.f, a1 = 0.f, a2 = 0.f, a3 = 0.f;
  const long rowbase = (long)b * 2048 + chunk * 128;
  for (int t = rg; t < 128; t += 4) {
    const float w = wLds[t];
    ushort4 v = src[(rowbase + t) * 64 + dg];
    a0 += w * bf2f(v.x); a1 += w * bf2f(v.y);
    a2 += w * bf2f(v.z); a3 += w * bf2f(v.w);
  }
  red[tid * 4 + 0] = a0; red[tid * 4 + 1] = a1;
  red[tid * 4 + 2] = a2; red[tid * 4 + 3] = a3;
  __syncthreads();
  if (tid < 64) {
    #pragma unroll
    for (int k = 0; k < 4; ++k) {
      float v = red[(0 * 64 + tid) * 4 + k] + red[(1 * 64 + tid) * 4 + k] +
                red[(2 * 64 + tid) * 4 + k] + red[(3 * 64 + tid) * 4 + k];
      atomicAdd(&out[z * 4096 + b * 256 + tid * 4 + k], v);
    }
  }
}

// ---------- launch ----------
extern "C" void kernel_launch(void* const* d_in, const int* in_sizes, int n_in,
                              void* d_out, int out_size, void* d_ws, size_t ws_size,
                              hipStream_t stream) {
  const float* q = (const float*)d_in[0];
  const float* a = (const float*)d_in[1];
  const float* U = (const float*)d_in[2];
  float* out = (float*)d_out;

  char* w = (char*)d_ws;
  unsigned short* qb = (unsigned short*)w;
  unsigned short* ab = (unsigned short*)(w + (16ull << 20));
  unsigned short* qU = (unsigned short*)(w + (32ull << 20));
  unsigned short* Ut = (unsigned short*)(w + (48ull << 20));
  unsigned* rmax = (unsigned*)(w + (48ull << 20) + (128ull << 10));
  unsigned* cmax = rmax + 32768;

  // rmax+cmax contiguous: one memset; 0 encodes below any real float
  hipMemsetAsync(rmax, 0, 2 * 32768 * sizeof(unsigned), stream);
  hipMemsetAsync(out, 0, 8192 * sizeof(float), stream);

  convert_qa_kernel<<<8192, 256, 0, stream>>>((const float4*)q, (const float4*)a,
                                              (ushort4*)qb, (ushort4*)ab);
  convert_u_kernel<<<256, 256, 0, stream>>>(U, Ut);

  // qU[m,n] = sum_k q[m,k] * Ut[n,k]; M = 32768, N = 256
  gemm_bt<2, 2, 0><<<dim3(256, 2, 1), 256, 0, stream>>>(qb, Ut, 0, 0, qU, nullptr, nullptr);

  // S row/col maxes per batch (2048x2048), 128x128 tiles
  gemm_bt<2, 2, 1><<<dim3(16, 16, 16), 256, 0, stream>>>(qU, ab, 2048 * 256, 2048 * 256,
                                                         nullptr, rmax, cmax);

  // fused softmax + weighted pooling (bf16 reads)
  wsum_kernel<<<dim3(16, 16, 2), 256, 0, stream>>>((const ushort4*)qb, (const ushort4*)ab,
                                                   rmax, cmax, out);
}

// Round 7
// 181.529 us; speedup vs baseline: 1.0463x; 1.0122x over previous
//
#include <hip/hip_runtime.h>
#include <stdint.h>

// ---------- types ----------
typedef __attribute__((ext_vector_type(8))) short s8v;   // 8 bf16 (4 VGPRs)
typedef __attribute__((ext_vector_type(4))) float f4v;   // MFMA accumulator

// ---------- helpers ----------
__device__ __forceinline__ unsigned short f2bf(float f) {
  unsigned u = __float_as_uint(f);
  u = u + 0x7FFFu + ((u >> 16) & 1u);   // RNE
  return (unsigned short)(u >> 16);
}
__device__ __forceinline__ float bf2f(unsigned short h) {
  return __uint_as_float((unsigned)h << 16);
}
// monotone float->uint map: order(enc(a)) == order(a); 0 is below enc of any real float.
__device__ __forceinline__ unsigned encf(float f) {
  unsigned i = __float_as_uint(f);
  return (i & 0x80000000u) ? ~i : (i | 0x80000000u);
}
__device__ __forceinline__ float decf(unsigned u) {
  unsigned i = (u & 0x80000000u) ? (u & 0x7FFFFFFFu) : ~u;
  return __uint_as_float(i);
}
__device__ __forceinline__ void gload_lds16(const unsigned short* g, unsigned short* l) {
  __builtin_amdgcn_global_load_lds((const __attribute__((address_space(1))) void*)g,
                                   (__attribute__((address_space(3))) void*)l, 16, 0, 0);
}

// ---------- fused conversions: q,a fp32->bf16; U fp32 -> Ut bf16 transposed ----------
__global__ void convert_kernel(const float4* __restrict__ q, const float4* __restrict__ a,
                               const float* __restrict__ U,
                               ushort4* __restrict__ qb, ushort4* __restrict__ ab,
                               unsigned short* __restrict__ Ut) {
  const int bx = blockIdx.x;
  if (bx < 8192) {
    const int i = bx * 256 + threadIdx.x;
    float4 v = q[i];
    qb[i] = make_ushort4(f2bf(v.x), f2bf(v.y), f2bf(v.z), f2bf(v.w));
    float4 w = a[i];
    ab[i] = make_ushort4(f2bf(w.x), f2bf(w.y), f2bf(w.z), f2bf(w.w));
  } else {
    // U transpose: 64 blocks x 256 thr, 4 elements each (tiny: 256 KB read)
    const int idx = (bx - 8192) * 256 + threadIdx.x;   // 0..16383
    const int n  = idx >> 6;
    const int k4 = (idx & 63) * 4;
    ushort4 o;
    o.x = f2bf(U[(k4 + 0) * 256 + n]);
    o.y = f2bf(U[(k4 + 1) * 256 + n]);
    o.z = f2bf(U[(k4 + 2) * 256 + n]);
    o.w = f2bf(U[(k4 + 3) * 256 + n]);
    *(ushort4*)&Ut[n * 256 + k4] = o;
  }
}

// ---------- GEMM C[m,n] = sum_k A[m,k]*B[n,k]  (row-major, K=256, ld=256) ----------
// 128x128 tile, 4 waves (2x2), 256 threads — the R4-verified config.
// LDS XOR-swizzled: element (row, 16B-chunk c) lives at chunk c ^ (row&7);
// staging permutes the GLOBAL source chunk (inverse; issue base rows mult of 8).
// MODE 0: store C bf16. MODE 1: row/col maxes -> encoded-uint atomics.
// MODE 1 grid: (b, tn, tm) => XCD (~linear%8) == b%8: each batch's 2MB working
// set (qU rows + a rows) pins to one XCD L2 (2 batches/XCD = 4MB = L2 size).
template<int WM, int WN, int MODE>
__global__ void gemm_bt(const unsigned short* __restrict__ A,
                        const unsigned short* __restrict__ Bm,
                        long strideA, long strideB,
                        unsigned short* __restrict__ C,
                        unsigned* __restrict__ rowmax,
                        unsigned* __restrict__ colmax) {
  constexpr int T = WM * WN * 64;        // threads
  constexpr int AROWS = WM * 64;
  constexpr int BROWS = WN * 64;
  constexpr int RPI = T / 8;             // rows staged per issue

  __shared__ unsigned short As[AROWS * 64];
  __shared__ unsigned short Bs[BROWS * 64];
  __shared__ unsigned rowLds[AROWS];
  __shared__ unsigned colLds[BROWS];

  const int tid = threadIdx.x;
  int tm, tn, b;
  if (MODE == 1) { b = blockIdx.x; tn = blockIdx.y; tm = blockIdx.z; }
  else           { tm = blockIdx.x; tn = blockIdx.y; b = blockIdx.z; }
  const unsigned short* Ab = A + (long)b * strideA + (long)tm * AROWS * 256;
  const unsigned short* Bb = Bm + (long)b * strideB + (long)tn * BROWS * 256;

  const int lane = tid & 63;
  const int m16  = lane & 15;
  const int quad = lane >> 4;
  const int wave = tid >> 6;
  const int wm   = wave / WN, wn = wave % WN;
  const int srow = tid >> 3;                                // staging row within issue
  const int scol = (((tid & 7) ^ (srow & 7))) * 8;          // swizzled global source chunk

  if (MODE == 1) {
    if (tid < AROWS) rowLds[tid] = 0u;
    if (tid < BROWS) colLds[tid] = 0u;
  }

  f4v acc[4][4] = {};

  for (int kt = 0; kt < 4; ++kt) {
    const int k0 = kt * 64;
    __syncthreads();                  // LDS free from previous iter
    #pragma unroll
    for (int i = 0; i < AROWS / RPI; ++i) {
      const int r = i * RPI + srow;
      gload_lds16(Ab + (long)r * 256 + k0 + scol, &As[i * RPI * 64 + tid * 8]);
    }
    #pragma unroll
    for (int i = 0; i < BROWS / RPI; ++i) {
      const int r = i * RPI + srow;
      gload_lds16(Bb + (long)r * 256 + k0 + scol, &Bs[i * RPI * 64 + tid * 8]);
    }
    __syncthreads();                  // staging complete
    #pragma unroll
    for (int kk = 0; kk < 2; ++kk) {
      const int cs = ((kk * 4 + quad) ^ (m16 & 7)) * 8;   // read swizzle (row&7 == m16&7)
      s8v af[4], bfv[4];
      #pragma unroll
      for (int i = 0; i < 4; ++i)
        af[i] = *(const s8v*)&As[(wm * 64 + i * 16 + m16) * 64 + cs];
      #pragma unroll
      for (int j = 0; j < 4; ++j)
        bfv[j] = *(const s8v*)&Bs[(wn * 64 + j * 16 + m16) * 64 + cs];
      #pragma unroll
      for (int i = 0; i < 4; ++i)
        #pragma unroll
        for (int j = 0; j < 4; ++j)
          acc[i][j] = __builtin_amdgcn_mfma_f32_16x16x32_bf16(af[i], bfv[j], acc[i][j], 0, 0, 0);
    }
  }

  if (MODE == 0) {
    // C/D layout: col = lane&15, row = quad*4 + reg  (verified mapping)
    #pragma unroll
    for (int i = 0; i < 4; ++i)
      #pragma unroll
      for (int r = 0; r < 4; ++r) {
        const long row = (long)tm * AROWS + wm * 64 + i * 16 + quad * 4 + r;
        #pragma unroll
        for (int j = 0; j < 4; ++j) {
          const int col = tn * BROWS + wn * 64 + j * 16 + m16;
          C[row * 256 + col] = f2bf(acc[i][j][r]);
        }
      }
  } else {
    // ---- row maxes ----
    #pragma unroll
    for (int i = 0; i < 4; ++i)
      #pragma unroll
      for (int r = 0; r < 4; ++r) {
        float v = fmaxf(fmaxf(acc[i][0][r], acc[i][1][r]), fmaxf(acc[i][2][r], acc[i][3][r]));
        #pragma unroll
        for (int d2 = 1; d2 < 16; d2 <<= 1) v = fmaxf(v, __shfl_xor(v, d2));
        if (m16 == 0) atomicMax(&rowLds[wm * 64 + i * 16 + quad * 4 + r], encf(v));
      }
    // ---- col maxes ----
    #pragma unroll
    for (int j = 0; j < 4; ++j) {
      float v = -3.4e38f;
      #pragma unroll
      for (int i = 0; i < 4; ++i)
        #pragma unroll
        for (int r = 0; r < 4; ++r) v = fmaxf(v, acc[i][j][r]);
      v = fmaxf(v, __shfl_xor(v, 16));
      v = fmaxf(v, __shfl_xor(v, 32));
      if (quad == 0) atomicMax(&colLds[wn * 64 + j * 16 + m16], encf(v));
    }
    __syncthreads();
    if (tid < AROWS) {
      atomicMax(&rowmax[(long)b * 2048 + tm * AROWS + tid], rowLds[tid]);
    } else if (tid < AROWS + BROWS) {
      atomicMax(&colmax[(long)b * 2048 + tn * BROWS + (tid - AROWS)], colLds[tid - AROWS]);
    }
  }
}

// ---------- fused softmax + weighted sum (bf16 inputs, fp32 accumulate) ----------
__global__ void wsum_kernel(const ushort4* __restrict__ qb, const ushort4* __restrict__ ab,
                            const unsigned* __restrict__ rowmax, const unsigned* __restrict__ colmax,
                            float* __restrict__ out) {
  const int tid = threadIdx.x;
  const int chunk = blockIdx.x;
  const int b = blockIdx.y;
  const int z = blockIdx.z;
  const unsigned* e = z ? colmax : rowmax;
  const ushort4* src = z ? ab : qb;

  __shared__ float sm[4];
  __shared__ float ss[4];
  __shared__ float wLds[128];
  __shared__ float red[256 * 4];

  // softmax stats over all 2048 positions of batch b
  float x[8];
  float m = -3.4e38f;
  #pragma unroll
  for (int j = 0; j < 8; ++j) {
    x[j] = tanhf(decf(e[b * 2048 + j * 256 + tid]));
    m = fmaxf(m, x[j]);
  }
  #pragma unroll
  for (int d2 = 1; d2 < 64; d2 <<= 1) m = fmaxf(m, __shfl_xor(m, d2));
  if ((tid & 63) == 0) sm[tid >> 6] = m;
  __syncthreads();
  m = fmaxf(fmaxf(sm[0], sm[1]), fmaxf(sm[2], sm[3]));
  float s = 0.f;
  #pragma unroll
  for (int j = 0; j < 8; ++j) s += expf(x[j] - m);
  #pragma unroll
  for (int d2 = 1; d2 < 64; d2 <<= 1) s += __shfl_xor(s, d2);
  if ((tid & 63) == 0) ss[tid >> 6] = s;
  __syncthreads();
  const float inv = 1.f / (ss[0] + ss[1] + ss[2] + ss[3]);

  // weights for this chunk's 128 rows
  if (tid < 128) {
    float xv = tanhf(decf(e[b * 2048 + chunk * 128 + tid]));
    wLds[tid] = expf(xv - m) * inv;
  }
  __syncthreads();

  const int dg = tid & 63;     // ushort4 index: d = dg*4..dg*4+3
  const int rg = tid >> 6;
  float a0 = 0.f, a1 = 0.f, a2 = 0.f, a3 = 0.f;
  const long rowbase = (long)b * 2048 + chunk * 128;
  for (int t = rg; t < 128; t += 4) {
    const float w = wLds[t];
    ushort4 v = src[(rowbase + t) * 64 + dg];
    a0 += w * bf2f(v.x); a1 += w * bf2f(v.y);
    a2 += w * bf2f(v.z); a3 += w * bf2f(v.w);
  }
  red[tid * 4 + 0] = a0; red[tid * 4 + 1] = a1;
  red[tid * 4 + 2] = a2; red[tid * 4 + 3] = a3;
  __syncthreads();
  if (tid < 64) {
    #pragma unroll
    for (int k = 0; k < 4; ++k) {
      float v = red[(0 * 64 + tid) * 4 + k] + red[(1 * 64 + tid) * 4 + k] +
                red[(2 * 64 + tid) * 4 + k] + red[(3 * 64 + tid) * 4 + k];
      atomicAdd(&out[z * 4096 + b * 256 + tid * 4 + k], v);
    }
  }
}

// ---------- launch ----------
extern "C" void kernel_launch(void* const* d_in, const int* in_sizes, int n_in,
                              void* d_out, int out_size, void* d_ws, size_t ws_size,
                              hipStream_t stream) {
  const float* q = (const float*)d_in[0];
  const float* a = (const float*)d_in[1];
  const float* U = (const float*)d_in[2];
  float* out = (float*)d_out;

  char* w = (char*)d_ws;
  unsigned short* qb = (unsigned short*)w;
  unsigned short* ab = (unsigned short*)(w + (16ull << 20));
  unsigned short* qU = (unsigned short*)(w + (32ull << 20));
  unsigned short* Ut = (unsigned short*)(w + (48ull << 20));
  unsigned* rmax = (unsigned*)(w + (48ull << 20) + (128ull << 10));
  unsigned* cmax = rmax + 32768;

  hipMemsetAsync(rmax, 0, 2 * 32768 * sizeof(unsigned), stream);
  hipMemsetAsync(out, 0, 8192 * sizeof(float), stream);

  // fused q/a bf16-cast + U transpose
  convert_kernel<<<8192 + 64, 256, 0, stream>>>((const float4*)q, (const float4*)a, U,
                                                (ushort4*)qb, (ushort4*)ab, Ut);

  // qU[m,n] = sum_k q[m,k]*Ut[n,k]; M=32768 tiles of 128, N=256 tiles of 128
  gemm_bt<2, 2, 0><<<dim3(256, 2, 1), 256, 0, stream>>>(qb, Ut, 0, 0, qU, nullptr, nullptr);

  // S row/col maxes per batch (2048x2048), 128x128 tiles; grid (b, tn, tm)
  gemm_bt<2, 2, 1><<<dim3(16, 16, 16), 256, 0, stream>>>(qU, ab, 2048 * 256, 2048 * 256,
                                                         nullptr, rmax, cmax);

  // fused softmax + weighted pooling (bf16 reads)
  wsum_kernel<<<dim3(16, 16, 2), 256, 0, stream>>>((const ushort4*)qb, (const ushort4*)ab,
                                                   rmax, cmax, out);
}